// Round 1
// baseline (377.905 us; speedup 1.0000x reference)
//
#include <hip/hip_runtime.h>
#include <stdint.h>
#include <stddef.h>

// Problem constants: B=4, H=16, P=1024, D=128
#define BHC 64
#define PP  1024
#define DD  128
#define BM  64      // q rows per block
#define BN  128     // keys per LDS chunk
#define NCH 8       // P / BN
#define LSTR 136    // LDS row stride in ushorts (128 + 8 pad = 272 B -> 2-way bank aliasing only)

typedef __bf16 bf16x8 __attribute__((ext_vector_type(8)));
typedef float  f32x4  __attribute__((ext_vector_type(4)));

__device__ __forceinline__ unsigned short f2bf(float x) {
    union { float f; uint32_t u; } v; v.f = x;
    uint32_t r = v.u + 0x7FFFu + ((v.u >> 16) & 1u);   // RNE
    return (unsigned short)(r >> 16);
}

// ---------------- silu + bf16 cast precompute ----------------
__global__ void silu_cast_kernel(const float* __restrict__ q, const float* __restrict__ k,
                                 unsigned short* __restrict__ qb, unsigned short* __restrict__ kb,
                                 int n4each) {
    int stride = gridDim.x * blockDim.x;
    int total  = 2 * n4each;
    for (int i = blockIdx.x * blockDim.x + threadIdx.x; i < total; i += stride) {
        const float4* s; ushort4* d; int j;
        if (i < n4each) { s = (const float4*)q; d = (ushort4*)qb; j = i; }
        else            { s = (const float4*)k; d = (ushort4*)kb; j = i - n4each; }
        float4 x = s[j];
        float4 y;
        y.x = x.x / (1.f + __expf(-x.x));
        y.y = x.y / (1.f + __expf(-x.y));
        y.z = x.z / (1.f + __expf(-x.z));
        y.w = x.w / (1.f + __expf(-x.w));
        ushort4 o;
        o.x = f2bf(y.x); o.y = f2bf(y.y); o.z = f2bf(y.z); o.w = f2bf(y.w);
        d[j] = o;
    }
}

// ---------------- fused scores + softmax ----------------
// 16 waves = 2 row-groups (wr) x 8 key-groups (wc).
// Wave (wr,wc): rows wr*32 + {0,16} (two 16-row MFMA tiles),
//               keys c*128 + wc*16 + (lane&15) for each chunk c.
// acc[c][rt] : f32x4 per lane -> 64 VGPRs holds the full 64x1024 stripe.
__global__ __launch_bounds__(1024) void attn_kernel(
        const unsigned short* __restrict__ qb, const unsigned short* __restrict__ kb,
        const float* __restrict__ scale, float* __restrict__ out) {
    __shared__ unsigned short qs [BM * LSTR];   // 17408 B
    __shared__ unsigned short ksm[BN * LSTR];   // 34816 B
    __shared__ float red_m[BM * 8];             // 2048 B
    __shared__ float red_l[BM * 8];             // 2048 B

    // XCD swizzle: all 16 q-blocks of a bh on one XCD (round-robin heuristic)
    int bx   = blockIdx.x;
    int xcd  = bx & 7;
    int idx  = bx >> 3;               // 0..127
    int bh   = xcd * 8 + (idx >> 4);  // 0..63
    int qblk = idx & 15;

    int t    = threadIdx.x;
    int lane = t & 63;
    int w    = t >> 6;
    int wr   = w & 1;
    int wc   = w >> 1;
    int l15  = lane & 15;
    int quad = lane >> 4;

    const unsigned short* qg = qb + (size_t)bh * (PP * DD) + (size_t)qblk * (BM * DD);
    const unsigned short* kg = kb + (size_t)bh * (PP * DD);

    // ---- stage Q tile (64 x 128 bf16): 1024 units of 16 B, coalesced ----
    {
        int row = t >> 4, u = t & 15;
        uint4 v = *(const uint4*)(qg + row * DD + u * 8);
        *(uint4*)(&qs[row * LSTR + u * 8]) = v;
    }
    __syncthreads();

    // ---- preload A fragments: A[m=lane&15][k=quad*8+j] ----
    bf16x8 aF[2][4];
#pragma unroll
    for (int rt = 0; rt < 2; ++rt)
#pragma unroll
        for (int kk = 0; kk < 4; ++kk)
            aF[rt][kk] = *(const bf16x8*)(&qs[(wr * 32 + rt * 16 + l15) * LSTR + kk * 32 + quad * 8]);

    f32x4 acc[NCH][2];
#pragma unroll
    for (int c = 0; c < NCH; ++c) {
        acc[c][0] = (f32x4)0.0f;
        acc[c][1] = (f32x4)0.0f;
    }

    // ---- K-chunk loop: stage 128 keys x 128 d, 4 k-steps x 2 row-tiles MFMA ----
#pragma unroll
    for (int c = 0; c < NCH; ++c) {
        __syncthreads();   // protect ksm from previous chunk's readers
        {
            int u0 = t,        r0 = u0 >> 4, c0 = u0 & 15;
            int u1 = t + 1024, r1 = u1 >> 4, c1 = u1 & 15;
            uint4 v0 = *(const uint4*)(kg + (c * BN + r0) * DD + c0 * 8);
            uint4 v1 = *(const uint4*)(kg + (c * BN + r1) * DD + c1 * 8);
            *(uint4*)(&ksm[r0 * LSTR + c0 * 8]) = v0;
            *(uint4*)(&ksm[r1 * LSTR + c1 * 8]) = v1;
        }
        __syncthreads();
#pragma unroll
        for (int kk = 0; kk < 4; ++kk) {
            bf16x8 bF = *(const bf16x8*)(&ksm[(wc * 16 + l15) * LSTR + kk * 32 + quad * 8]);
            acc[c][0] = __builtin_amdgcn_mfma_f32_16x16x32_bf16(aF[0][kk], bF, acc[c][0], 0, 0, 0);
            acc[c][1] = __builtin_amdgcn_mfma_f32_16x16x32_bf16(aF[1][kk], bF, acc[c][1], 0, 0, 0);
        }
    }

    // ---- softmax over keys (scale folded into exp2 argument) ----
    float C2 = scale[0] * 1.44269504088896340736f;  // scale * log2(e)

    // per-row max: in-lane over chunks, shuffle-xor over the 16 cols, LDS across 8 wc groups
#pragma unroll
    for (int rt = 0; rt < 2; ++rt) {
#pragma unroll
        for (int r = 0; r < 4; ++r) {
            float m = acc[0][rt][r];
#pragma unroll
            for (int c = 1; c < NCH; ++c) m = fmaxf(m, acc[c][rt][r]);
#pragma unroll
            for (int off = 1; off < 16; off <<= 1) m = fmaxf(m, __shfl_xor(m, off, 64));
            if (l15 == 0) red_m[(wr * 32 + rt * 16 + quad * 4 + r) * 8 + wc] = m;
        }
    }
    __syncthreads();

#pragma unroll
    for (int rt = 0; rt < 2; ++rt) {
#pragma unroll
        for (int r = 0; r < 4; ++r) {
            int row = wr * 32 + rt * 16 + quad * 4 + r;
            float4 p0 = *(const float4*)(&red_m[row * 8]);
            float4 p1 = *(const float4*)(&red_m[row * 8 + 4]);
            float m = fmaxf(fmaxf(fmaxf(p0.x, p0.y), fmaxf(p0.z, p0.w)),
                            fmaxf(fmaxf(p1.x, p1.y), fmaxf(p1.z, p1.w)));
            float ssum = 0.f;
#pragma unroll
            for (int c = 0; c < NCH; ++c) {
                float e = exp2f((acc[c][rt][r] - m) * C2);
                acc[c][rt][r] = e;
                ssum += e;
            }
#pragma unroll
            for (int off = 1; off < 16; off <<= 1) ssum += __shfl_xor(ssum, off, 64);
            if (l15 == 0) red_l[row * 8 + wc] = ssum;
        }
    }
    __syncthreads();

    float inv[2][4];
#pragma unroll
    for (int rt = 0; rt < 2; ++rt) {
#pragma unroll
        for (int r = 0; r < 4; ++r) {
            int row = wr * 32 + rt * 16 + quad * 4 + r;
            float4 p0 = *(const float4*)(&red_l[row * 8]);
            float4 p1 = *(const float4*)(&red_l[row * 8 + 4]);
            float l = (p0.x + p0.y) + (p0.z + p0.w) + (p1.x + p1.y) + (p1.z + p1.w);
            inv[rt][r] = 1.0f / l;
        }
    }

    // ---- store: lane&15 contiguous keys -> 64 B segments per quarter-wave ----
    float* og = out + ((size_t)bh << 20) + (size_t)(qblk * BM) * PP;
#pragma unroll
    for (int c = 0; c < NCH; ++c) {
#pragma unroll
        for (int rt = 0; rt < 2; ++rt) {
            int key = c * BN + wc * 16 + l15;
            int rb  = wr * 32 + rt * 16 + quad * 4;
#pragma unroll
            for (int r = 0; r < 4; ++r) {
                og[(size_t)(rb + r) * PP + key] = acc[c][rt][r] * inv[rt][r];
            }
        }
    }
}

extern "C" void kernel_launch(void* const* d_in, const int* in_sizes, int n_in,
                              void* d_out, int out_size, void* d_ws, size_t ws_size,
                              hipStream_t stream) {
    const float* q     = (const float*)d_in[0];
    const float* k     = (const float*)d_in[1];
    const float* scale = (const float*)d_in[2];
    float* out = (float*)d_out;

    // workspace: silu(q), silu(k) as bf16 (2 x 16 MB = 32 MB)
    unsigned short* qb = (unsigned short*)d_ws;
    unsigned short* kb = qb + (size_t)BHC * PP * DD;

    int n4each = (BHC * PP * DD) / 4;   // float4 units per tensor
    silu_cast_kernel<<<2048, 256, 0, stream>>>(q, k, qb, kb, n4each);
    attn_kernel<<<1024, 1024, 0, stream>>>(qb, kb, scale, out);
}